// Round 1
// baseline (125.124 us; speedup 1.0000x reference)
//
#include <hip/hip_runtime.h>
#include <stdint.h>

// Binarized dense: C[r][u] = sum_k sign(x[r][k]) * sign(W[k][u]) + b[u]
//   sign(v) = +1 if v >= 0 else -1   -> bit(v) = (v < 0)
//   dot = F - 2 * popcount(xbits ^ wbits)
//
// Packed layout per row/col (F=4096 bits = 64 u64 words):
//   word index w = c*4 + j,  c = 0..15 (256-float chunk), j = 0..3 (float4 comp)
//   bit i (0..63) of word (c,j) = bit(v[c*256 + i*4 + j])
// This matches __ballot() on float4 components with lane i holding float4 #i.

#define BATCH  16384
#define INF    4096
#define UNITS  512
#define KW     128      // u32 words per row (4096/32)
#define KW64   64       // u64 words per row

// ---------------- pack x: [16384,4096] f32 -> [16384,64] u64 ----------------
__global__ __launch_bounds__(256) void pack_x_kernel(const float* __restrict__ x,
                                                     unsigned long long* __restrict__ Xp) {
    int wave = blockIdx.x * 4 + (threadIdx.x >> 6);
    int lane = threadIdx.x & 63;
    int r = wave >> 4;        // row 0..16383
    int c = wave & 15;        // 256-float chunk 0..15
    const float4 v = reinterpret_cast<const float4*>(x + (size_t)r * INF + c * 256)[lane];
    unsigned long long b0 = __ballot(v.x < 0.f);
    unsigned long long b1 = __ballot(v.y < 0.f);
    unsigned long long b2 = __ballot(v.z < 0.f);
    unsigned long long b3 = __ballot(v.w < 0.f);
    if (lane == 0) {
        unsigned long long* dst = Xp + (size_t)r * KW64 + c * 4;
        dst[0] = b0; dst[1] = b1; dst[2] = b2; dst[3] = b3;
    }
}

// ---------------- pack W: [4096,512] f32 -> [512,64] u64 --------------------
__global__ __launch_bounds__(256) void pack_w_kernel(const float* __restrict__ W,
                                                     unsigned long long* __restrict__ Wp) {
    int t  = blockIdx.x * 256 + threadIdx.x;   // 0..32767
    int u  = t & 511;                          // column
    int cj = t >> 9;                           // 0..63 = c*4 + j
    int j  = cj & 3;
    int c  = cj >> 2;
    const float* base = W + (size_t)(c * 256 + j) * UNITS + u;
    unsigned long long m = 0;
    #pragma unroll 16
    for (int i = 0; i < 64; ++i) {
        // k = c*256 + 4*i + j ; addr = k*512 + u
        float v = base[(size_t)(4 * i) * UNITS];
        m |= (unsigned long long)(v < 0.f) << i;
    }
    Wp[(size_t)u * KW64 + cj] = m;
}

// ---------------- bit-GEMM: 64x64 tile, 4x4 per thread ----------------------
// sX/sW stride 132 words (528B, 16B-aligned): row r -> bank shift 4r mod 32.
// X reads: rows ty+16i, ty in 0..3 per wave -> banks {0,4,8,12}: conflict-free.
// W reads: cols tx+16j, tx in 0..15 -> 2-way conflict (free per m136).
__global__ __launch_bounds__(256) void bgemm_kernel(const uint32_t* __restrict__ Xp,
                                                    const uint32_t* __restrict__ Wp,
                                                    const float* __restrict__ bias,
                                                    float* __restrict__ C) {
    __shared__ uint32_t sX[64][132];
    __shared__ uint32_t sW[64][132];
    const int t  = threadIdx.x;
    const int bx = blockIdx.x;   // N tile 0..7
    const int by = blockIdx.y;   // M tile 0..255

    const uint4* gX = reinterpret_cast<const uint4*>(Xp + (size_t)by * 64 * KW);
    const uint4* gW = reinterpret_cast<const uint4*>(Wp + (size_t)bx * 64 * KW);
    #pragma unroll
    for (int i = 0; i < 8; ++i) {
        int idx4 = t + 256 * i;          // uint4 index, 2048 total (64 rows * 32)
        int row  = idx4 >> 5;
        int col  = (idx4 & 31) * 4;
        *reinterpret_cast<uint4*>(&sX[row][col]) = gX[idx4];
        *reinterpret_cast<uint4*>(&sW[row][col]) = gW[idx4];
    }
    __syncthreads();

    const int tx = t & 15;       // col group
    const int ty = t >> 4;       // row group
    int acc[4][4] = {};

    #pragma unroll 4
    for (int k4 = 0; k4 < 32; ++k4) {
        uint4 xv[4], wv[4];
        #pragma unroll
        for (int i = 0; i < 4; ++i)
            xv[i] = *reinterpret_cast<const uint4*>(&sX[ty + 16 * i][k4 * 4]);
        #pragma unroll
        for (int j = 0; j < 4; ++j)
            wv[j] = *reinterpret_cast<const uint4*>(&sW[tx + 16 * j][k4 * 4]);
        #pragma unroll
        for (int i = 0; i < 4; ++i)
            #pragma unroll
            for (int j = 0; j < 4; ++j) {
                acc[i][j] += __popc(xv[i].x ^ wv[j].x);
                acc[i][j] += __popc(xv[i].y ^ wv[j].y);
                acc[i][j] += __popc(xv[i].z ^ wv[j].z);
                acc[i][j] += __popc(xv[i].w ^ wv[j].w);
            }
    }

    #pragma unroll
    for (int i = 0; i < 4; ++i) {
        int r = by * 64 + ty + 16 * i;
        #pragma unroll
        for (int j = 0; j < 4; ++j) {
            int u = bx * 64 + tx + 16 * j;
            C[(size_t)r * UNITS + u] = (float)(INF - 2 * acc[i][j]) + bias[u];
        }
    }
}

extern "C" void kernel_launch(void* const* d_in, const int* in_sizes, int n_in,
                              void* d_out, int out_size, void* d_ws, size_t ws_size,
                              hipStream_t stream) {
    const float* x = (const float*)d_in[0];
    const float* W = (const float*)d_in[1];
    const float* b = (const float*)d_in[2];
    float* out = (float*)d_out;

    unsigned long long* Wp = (unsigned long long*)d_ws;                       // 256 KB
    unsigned long long* Xp = (unsigned long long*)((char*)d_ws + (1 << 20));  // 8 MB

    pack_w_kernel<<<32768 / 256, 256, 0, stream>>>(W, Wp);
    pack_x_kernel<<<(BATCH * 16) / 4, 256, 0, stream>>>(x, Xp);
    bgemm_kernel<<<dim3(UNITS / 64, BATCH / 64), 256, 0, stream>>>(
        (const uint32_t*)Xp, (const uint32_t*)Wp, b, out);
}